// Round 1
// baseline (1420.693 us; speedup 1.0000x reference)
//
#include <hip/hip_runtime.h>

#define HIDDEN 4096
#define HEADD  512
#define SEQ    2048
#define NBATCH 4

typedef float f32x4 __attribute__((ext_vector_type(4)));
typedef short s16x8 __attribute__((ext_vector_type(8)));

__device__ __forceinline__ unsigned short f2bf(float x){
  unsigned u = __float_as_uint(x);
  u += 0x7fffu + ((u >> 16) & 1u);
  return (unsigned short)(u >> 16);
}
__device__ __forceinline__ float bf2f(unsigned short b){
  return __uint_as_float(((unsigned)b) << 16);
}

// ---------------- Kernel 1: split weights fp32 -> bf16 hi/lo ----------------
__global__ void wsplit_kernel(const float* __restrict__ Wq,
                              const float* __restrict__ Wk,
                              const float* __restrict__ Wv,
                              unsigned short* __restrict__ wqh, unsigned short* __restrict__ wql,
                              unsigned short* __restrict__ wkh, unsigned short* __restrict__ wkl,
                              unsigned short* __restrict__ wvh){
  const int n = HEADD * HIDDEN;
  for (int i = blockIdx.x * blockDim.x + threadIdx.x; i < n; i += gridDim.x * blockDim.x){
    float a = Wq[i]; unsigned short h = f2bf(a);
    wqh[i] = h; wql[i] = f2bf(a - bf2f(h));
    a = Wk[i]; h = f2bf(a);
    wkh[i] = h; wkl[i] = f2bf(a - bf2f(h));
    wvh[i] = f2bf(Wv[i]);
  }
}

// ---------------- Kernel 2: projection GEMM C[8192,512] = X[8192,4096] * W[512,4096]^T
// SPLITS=3: split-bf16 (hh + hl + lh), MODE=0: write hi/lo bf16 outputs
// SPLITS=1: plain bf16,                MODE=1: write transposed bf16 (vhT[b][d][t])
template<int SPLITS, int MODE>
__global__ __launch_bounds__(256)
void proj_kernel(const float* __restrict__ X,
                 const unsigned short* __restrict__ Wh,
                 const unsigned short* __restrict__ Wl,
                 unsigned short* __restrict__ Ohi,
                 unsigned short* __restrict__ Olo,
                 unsigned short* __restrict__ OvT){
  __shared__ unsigned short Ah[128*32];
  __shared__ unsigned short Al[128*32];
  __shared__ unsigned short Bh[128*32];
  __shared__ unsigned short Bl[128*32];

  const int tid  = threadIdx.x;
  const int lane = tid & 63, wid = tid >> 6;
  const int quad = lane >> 4, l16 = lane & 15;
  const int wm = wid >> 1, wn = wid & 1;
  const int m0 = blockIdx.y * 128, n0 = blockIdx.x * 128;

  f32x4 acc[4][4];
  #pragma unroll
  for (int i = 0; i < 4; i++)
    #pragma unroll
    for (int j = 0; j < 4; j++){
      f32x4 z = {0.f, 0.f, 0.f, 0.f};
      acc[i][j] = z;
    }

  for (int k0 = 0; k0 < HIDDEN; k0 += 32){
    // ---- stage A (fp32 -> bf16 hi/lo in LDS) ----
    #pragma unroll
    for (int c = 0; c < 4; c++){
      int chunk = tid + c * 256;
      int r  = chunk >> 3;
      int c4 = (chunk & 7) << 2;
      const float4 x = *(const float4*)(X + (size_t)(m0 + r) * HIDDEN + k0 + c4);
      ushort4 hv, lv;
      hv.x = f2bf(x.x); hv.y = f2bf(x.y); hv.z = f2bf(x.z); hv.w = f2bf(x.w);
      *(ushort4*)(Ah + r*32 + c4) = hv;
      if (SPLITS >= 3){
        lv.x = f2bf(x.x - bf2f(hv.x));
        lv.y = f2bf(x.y - bf2f(hv.y));
        lv.z = f2bf(x.z - bf2f(hv.z));
        lv.w = f2bf(x.w - bf2f(hv.w));
        *(ushort4*)(Al + r*32 + c4) = lv;
      }
    }
    // ---- stage B (pre-split bf16 weights) ----
    #pragma unroll
    for (int c = 0; c < 2; c++){
      int chunk = tid + c * 256;
      int nrow = chunk >> 2;
      int k8   = (chunk & 3) << 3;
      *(s16x8*)(Bh + nrow*32 + k8) =
          *(const s16x8*)(Wh + (size_t)(n0 + nrow) * HIDDEN + k0 + k8);
      if (SPLITS >= 3)
        *(s16x8*)(Bl + nrow*32 + k8) =
            *(const s16x8*)(Wl + (size_t)(n0 + nrow) * HIDDEN + k0 + k8);
    }
    __syncthreads();

    s16x8 ah[4], al[4], bh[4], bl[4];
    #pragma unroll
    for (int i = 0; i < 4; i++){
      ah[i] = *(const s16x8*)(Ah + (wm*64 + i*16 + l16)*32 + quad*8);
      if (SPLITS >= 3) al[i] = *(const s16x8*)(Al + (wm*64 + i*16 + l16)*32 + quad*8);
    }
    #pragma unroll
    for (int j = 0; j < 4; j++){
      bh[j] = *(const s16x8*)(Bh + (wn*64 + j*16 + l16)*32 + quad*8);
      if (SPLITS >= 3) bl[j] = *(const s16x8*)(Bl + (wn*64 + j*16 + l16)*32 + quad*8);
    }
    #pragma unroll
    for (int i = 0; i < 4; i++)
      #pragma unroll
      for (int j = 0; j < 4; j++){
        acc[i][j] = __builtin_amdgcn_mfma_f32_16x16x32_bf16(ah[i], bh[j], acc[i][j], 0, 0, 0);
        if (SPLITS >= 3){
          acc[i][j] = __builtin_amdgcn_mfma_f32_16x16x32_bf16(ah[i], bl[j], acc[i][j], 0, 0, 0);
          acc[i][j] = __builtin_amdgcn_mfma_f32_16x16x32_bf16(al[i], bh[j], acc[i][j], 0, 0, 0);
        }
      }
    __syncthreads();
  }

  if (MODE == 0){
    #pragma unroll
    for (int i = 0; i < 4; i++)
      #pragma unroll
      for (int j = 0; j < 4; j++)
        #pragma unroll
        for (int r = 0; r < 4; r++){
          int m = m0 + wm*64 + i*16 + quad*4 + r;
          int n = n0 + wn*64 + j*16 + l16;
          float c = acc[i][j][r];
          unsigned short h = f2bf(c);
          Ohi[(size_t)m * HEADD + n] = h;
          Olo[(size_t)m * HEADD + n] = f2bf(c - bf2f(h));
        }
  } else {
    #pragma unroll
    for (int i = 0; i < 4; i++)
      #pragma unroll
      for (int j = 0; j < 4; j++){
        int mbase = m0 + wm*64 + i*16 + quad*4;
        int d = n0 + wn*64 + j*16 + l16;
        int b = mbase >> 11;        // /2048
        int t = mbase & 2047;
        ushort4 v;
        v.x = f2bf(acc[i][j][0]);
        v.y = f2bf(acc[i][j][1]);
        v.z = f2bf(acc[i][j][2]);
        v.w = f2bf(acc[i][j][3]);
        *(ushort4*)(OvT + ((size_t)(b * HEADD + d)) * SEQ + t) = v;
      }
  }
}

// ---------------- Kernel 3: flash attention ----------------
// grid (64 q-tiles, 4 batches), 256 threads. Q-tile=32 rows, K-tile=64 keys.
// QK: waves 2x2 (wq: 16 q rows each, wk: 32 keys each), 4-term split-bf16.
// PV: each wave owns 128 of 512 head dims; P via LDS (C-layout -> A-layout).
__global__ __launch_bounds__(256)
void flash_kernel(const unsigned short* __restrict__ qhh, const unsigned short* __restrict__ qhl,
                  const unsigned short* __restrict__ khh, const unsigned short* __restrict__ khl,
                  const unsigned short* __restrict__ vhT, const int* __restrict__ mask,
                  float* __restrict__ out){
  __shared__ unsigned short Pls[32*64];
  __shared__ float redm[2][32];
  __shared__ float reds[2][32];
  __shared__ float m_row[32], l_row[32], mnew_s[32], alpha_s[32];

  const int tid = threadIdx.x, lane = tid & 63, wid = tid >> 6;
  const int quad = lane >> 4, l16 = lane & 15;
  const int wq = wid >> 1, wk = wid & 1;
  const int b = blockIdx.y, q0 = blockIdx.x * 32;

  if (tid < 32){ m_row[tid] = -3.0e38f; l_row[tid] = 0.f; }
  f32x4 oacc[2][8];
  #pragma unroll
  for (int i = 0; i < 2; i++)
    #pragma unroll
    for (int j = 0; j < 8; j++){
      f32x4 z = {0.f, 0.f, 0.f, 0.f};
      oacc[i][j] = z;
    }
  __syncthreads();

  const size_t qbase = ((size_t)(b * SEQ) + q0 + wq*16 + l16) * HEADD + quad*8;

  for (int kb = 0; kb < SEQ; kb += 64){
    // ---- QK^T: S-subtile [16 q x 32 k] per wave, 4-term split ----
    f32x4 s0 = {0.f,0.f,0.f,0.f}, s1 = {0.f,0.f,0.f,0.f};
    const int key0 = kb + wk*32 + l16;
    const int key1 = key0 + 16;
    const size_t kbase0 = ((size_t)(b * SEQ) + key0) * HEADD + quad*8;
    const size_t kbase1 = ((size_t)(b * SEQ) + key1) * HEADD + quad*8;
    #pragma unroll 4
    for (int d0 = 0; d0 < HEADD; d0 += 32){
      s16x8 aH  = *(const s16x8*)(qhh + qbase  + d0);
      s16x8 aL  = *(const s16x8*)(qhl + qbase  + d0);
      s16x8 b0H = *(const s16x8*)(khh + kbase0 + d0);
      s16x8 b0L = *(const s16x8*)(khl + kbase0 + d0);
      s16x8 b1H = *(const s16x8*)(khh + kbase1 + d0);
      s16x8 b1L = *(const s16x8*)(khl + kbase1 + d0);
      s0 = __builtin_amdgcn_mfma_f32_16x16x32_bf16(aH, b0H, s0, 0, 0, 0);
      s0 = __builtin_amdgcn_mfma_f32_16x16x32_bf16(aH, b0L, s0, 0, 0, 0);
      s0 = __builtin_amdgcn_mfma_f32_16x16x32_bf16(aL, b0H, s0, 0, 0, 0);
      s0 = __builtin_amdgcn_mfma_f32_16x16x32_bf16(aL, b0L, s0, 0, 0, 0);
      s1 = __builtin_amdgcn_mfma_f32_16x16x32_bf16(aH, b1H, s1, 0, 0, 0);
      s1 = __builtin_amdgcn_mfma_f32_16x16x32_bf16(aH, b1L, s1, 0, 0, 0);
      s1 = __builtin_amdgcn_mfma_f32_16x16x32_bf16(aL, b1H, s1, 0, 0, 0);
      s1 = __builtin_amdgcn_mfma_f32_16x16x32_bf16(aL, b1L, s1, 0, 0, 0);
    }
    // ---- scale + mask (replace, like reference) ----
    const int mk0 = mask[b * SEQ + key0];
    const int mk1 = mask[b * SEQ + key1];
    float sm0[4], sm1[4];
    #pragma unroll
    for (int r = 0; r < 4; r++){
      sm0[r] = mk0 ? s0[r] * 64.0f : -1.0e9f;
      sm1[r] = mk1 ? s1[r] * 64.0f : -1.0e9f;
    }
    // ---- row max (within quad: 16 lanes hold 16 key-cols) ----
    float rm[4];
    #pragma unroll
    for (int r = 0; r < 4; r++) rm[r] = fmaxf(sm0[r], sm1[r]);
    #pragma unroll
    for (int sh = 1; sh < 16; sh <<= 1){
      #pragma unroll
      for (int r = 0; r < 4; r++) rm[r] = fmaxf(rm[r], __shfl_xor(rm[r], sh, 64));
    }
    if (l16 == 0){
      #pragma unroll
      for (int r = 0; r < 4; r++) redm[wk][wq*16 + quad*4 + r] = rm[r];
    }
    __syncthreads();
    if (tid < 32){
      float mt = fmaxf(redm[0][tid], redm[1][tid]);
      float mo = m_row[tid];
      float mn = fmaxf(mo, mt);
      mnew_s[tid]  = mn;
      alpha_s[tid] = __expf(mo - mn);
      m_row[tid]   = mn;
    }
    __syncthreads();
    // ---- p = exp(s - m_new), write P to LDS, row sums ----
    float rs[4];
    #pragma unroll
    for (int r = 0; r < 4; r++){
      int row = wq*16 + quad*4 + r;
      float mn = mnew_s[row];
      float p0 = __expf(sm0[r] - mn);
      float p1 = __expf(sm1[r] - mn);
      rs[r] = p0 + p1;
      Pls[row*64 + wk*32 + l16]      = f2bf(p0);
      Pls[row*64 + wk*32 + 16 + l16] = f2bf(p1);
    }
    #pragma unroll
    for (int sh = 1; sh < 16; sh <<= 1){
      #pragma unroll
      for (int r = 0; r < 4; r++) rs[r] += __shfl_xor(rs[r], sh, 64);
    }
    if (l16 == 0){
      #pragma unroll
      for (int r = 0; r < 4; r++) reds[wk][wq*16 + quad*4 + r] = rs[r];
    }
    __syncthreads();
    if (tid < 32)
      l_row[tid] = l_row[tid] * alpha_s[tid] + reds[0][tid] + reds[1][tid];
    // ---- rescale O, then PV ----
    #pragma unroll
    for (int i = 0; i < 2; i++){
      float a0 = alpha_s[i*16 + quad*4 + 0];
      float a1 = alpha_s[i*16 + quad*4 + 1];
      float a2 = alpha_s[i*16 + quad*4 + 2];
      float a3 = alpha_s[i*16 + quad*4 + 3];
      #pragma unroll
      for (int j = 0; j < 8; j++){
        oacc[i][j][0] *= a0;
        oacc[i][j][1] *= a1;
        oacc[i][j][2] *= a2;
        oacc[i][j][3] *= a3;
      }
    }
    #pragma unroll
    for (int ks = 0; ks < 2; ks++){
      s16x8 pa0 = *(const s16x8*)(Pls + (l16)*64      + ks*32 + quad*8);
      s16x8 pa1 = *(const s16x8*)(Pls + (16 + l16)*64 + ks*32 + quad*8);
      #pragma unroll
      for (int j = 0; j < 8; j++){
        int d = wid*128 + j*16 + l16;
        s16x8 vb = *(const s16x8*)(vhT + ((size_t)(b * HEADD + d)) * SEQ + kb + ks*32 + quad*8);
        oacc[0][j] = __builtin_amdgcn_mfma_f32_16x16x32_bf16(pa0, vb, oacc[0][j], 0, 0, 0);
        oacc[1][j] = __builtin_amdgcn_mfma_f32_16x16x32_bf16(pa1, vb, oacc[1][j], 0, 0, 0);
      }
    }
    __syncthreads();
  }

  // ---- epilogue: divide by l, store ----
  float inv[2][4];
  #pragma unroll
  for (int i = 0; i < 2; i++)
    #pragma unroll
    for (int r = 0; r < 4; r++)
      inv[i][r] = 1.0f / l_row[i*16 + quad*4 + r];
  #pragma unroll
  for (int i = 0; i < 2; i++)
    #pragma unroll
    for (int j = 0; j < 8; j++)
      #pragma unroll
      for (int r = 0; r < 4; r++){
        int qrow = q0 + i*16 + quad*4 + r;
        int d = wid*128 + j*16 + l16;
        out[((size_t)(b * SEQ) + qrow) * HEADD + d] = oacc[i][j][r] * inv[i][r];
      }
}

extern "C" void kernel_launch(void* const* d_in, const int* in_sizes, int n_in,
                              void* d_out, int out_size, void* d_ws, size_t ws_size,
                              hipStream_t stream){
  const float* q    = (const float*)d_in[0];
  const float* k    = (const float*)d_in[1];
  const float* v    = (const float*)d_in[2];
  const int*   mask = (const int*)d_in[3];
  const float* Wq   = (const float*)d_in[4];
  const float* Wk   = (const float*)d_in[5];
  const float* Wv   = (const float*)d_in[6];
  float* out = (float*)d_out;

  char* ws = (char*)d_ws;
  const size_t MB = 1024 * 1024;
  unsigned short* wqh = (unsigned short*)(ws + 0*MB);
  unsigned short* wql = (unsigned short*)(ws + 4*MB);
  unsigned short* wkh = (unsigned short*)(ws + 8*MB);
  unsigned short* wkl = (unsigned short*)(ws + 12*MB);
  unsigned short* wvh = (unsigned short*)(ws + 16*MB);
  unsigned short* qhh = (unsigned short*)(ws + 20*MB);
  unsigned short* qhl = (unsigned short*)(ws + 28*MB);
  unsigned short* khh = (unsigned short*)(ws + 36*MB);
  unsigned short* khl = (unsigned short*)(ws + 44*MB);
  unsigned short* vhT = (unsigned short*)(ws + 52*MB);  // total 60 MB

  hipLaunchKernelGGL(wsplit_kernel, dim3(1024), dim3(256), 0, stream,
                     Wq, Wk, Wv, wqh, wql, wkh, wkl, wvh);
  hipLaunchKernelGGL((proj_kernel<3,0>), dim3(4, 64), dim3(256), 0, stream,
                     q, wqh, wql, qhh, qhl, (unsigned short*)nullptr);
  hipLaunchKernelGGL((proj_kernel<3,0>), dim3(4, 64), dim3(256), 0, stream,
                     k, wkh, wkl, khh, khl, (unsigned short*)nullptr);
  hipLaunchKernelGGL((proj_kernel<1,1>), dim3(4, 64), dim3(256), 0, stream,
                     v, wvh, wvh, (unsigned short*)nullptr, (unsigned short*)nullptr, vhT);
  hipLaunchKernelGGL(flash_kernel, dim3(64, 4), dim3(256), 0, stream,
                     qhh, qhl, khh, khl, vhT, mask, out);
}

// Round 2
// 1249.986 us; speedup vs baseline: 1.1366x; 1.1366x over previous
//
#include <hip/hip_runtime.h>

#define HIDDEN 4096
#define HEADD  512
#define SEQ    2048
#define NBATCH 4
#define FK     256   // keys staged per kb iteration in flash

typedef float f32x4 __attribute__((ext_vector_type(4)));
typedef short s16x8 __attribute__((ext_vector_type(8)));

__device__ __forceinline__ unsigned short f2bf(float x){
  unsigned u = __float_as_uint(x);
  u += 0x7fffu + ((u >> 16) & 1u);
  return (unsigned short)(u >> 16);
}
__device__ __forceinline__ float bf2f(unsigned short b){
  return __uint_as_float(((unsigned)b) << 16);
}
// async global->LDS, 16B per lane. lds base must be wave-uniform; lane i lands at base + i*16.
__device__ __forceinline__ void gl_lds16(const unsigned short* g, unsigned short* l){
  __builtin_amdgcn_global_load_lds((const __attribute__((address_space(1))) unsigned int*)g,
                                   (__attribute__((address_space(3))) unsigned int*)l,
                                   16, 0, 0);
}

// ---------------- Kernel 1: split weights fp32 -> bf16 hi/lo ----------------
__global__ void wsplit_kernel(const float* __restrict__ Wq,
                              const float* __restrict__ Wk,
                              const float* __restrict__ Wv,
                              unsigned short* __restrict__ wqh, unsigned short* __restrict__ wql,
                              unsigned short* __restrict__ wkh, unsigned short* __restrict__ wkl,
                              unsigned short* __restrict__ wvh){
  const int n = HEADD * HIDDEN;
  for (int i = blockIdx.x * blockDim.x + threadIdx.x; i < n; i += gridDim.x * blockDim.x){
    float a = Wq[i]; unsigned short h = f2bf(a);
    wqh[i] = h; wql[i] = f2bf(a - bf2f(h));
    a = Wk[i]; h = f2bf(a);
    wkh[i] = h; wkl[i] = f2bf(a - bf2f(h));
    wvh[i] = f2bf(Wv[i]);
  }
}

// ---------------- Kernel 2: projection GEMM C[8192,512] = X[8192,4096] * W[512,4096]^T
// 512 threads = 8 waves (wm 4 x wn 2). B staged via global_load_lds (pre-split bf16).
// A staged with in-register fp32->hi/lo conversion (converts each element once).
template<int SPLITS, int MODE>
__global__ __launch_bounds__(512, 2)
void proj_kernel(const float* __restrict__ X,
                 const unsigned short* __restrict__ Wh,
                 const unsigned short* __restrict__ Wl,
                 unsigned short* __restrict__ Ohi,
                 unsigned short* __restrict__ Olo,
                 unsigned short* __restrict__ OvT){
  __shared__ unsigned short Ah[128*32];
  __shared__ unsigned short Al[128*32];
  __shared__ unsigned short Bh[128*32];
  __shared__ unsigned short Bl[128*32];

  const int tid  = threadIdx.x;
  const int lane = tid & 63, wid = tid >> 6;      // 8 waves
  const int quad = lane >> 4, l16 = lane & 15;
  const int wm = wid >> 1, wn = wid & 1;          // 4 x 2 wave grid
  const int m0 = blockIdx.y * 128, n0 = blockIdx.x * 128;
  const int srow  = lane >> 2;                    // staging: row within 16-row segment
  const int skoff = (lane & 3) << 3;              // staging: k-offset (x8 shorts)

  f32x4 acc[2][4];
  #pragma unroll
  for (int i = 0; i < 2; i++)
    #pragma unroll
    for (int j = 0; j < 4; j++){
      f32x4 z = {0.f, 0.f, 0.f, 0.f};
      acc[i][j] = z;
    }

  for (int k0 = 0; k0 < HIDDEN; k0 += 32){
    // ---- stage A (fp32 -> bf16 hi/lo in LDS), 2 float4 per thread ----
    #pragma unroll
    for (int c = 0; c < 2; c++){
      int chunk = tid + c * 512;
      int r  = chunk >> 3;
      int c4 = (chunk & 7) << 2;
      const float4 x = *(const float4*)(X + (size_t)(m0 + r) * HIDDEN + k0 + c4);
      ushort4 hv, lv;
      hv.x = f2bf(x.x); hv.y = f2bf(x.y); hv.z = f2bf(x.z); hv.w = f2bf(x.w);
      *(ushort4*)(Ah + r*32 + c4) = hv;
      if (SPLITS >= 3){
        lv.x = f2bf(x.x - bf2f(hv.x));
        lv.y = f2bf(x.y - bf2f(hv.y));
        lv.z = f2bf(x.z - bf2f(hv.z));
        lv.w = f2bf(x.w - bf2f(hv.w));
        *(ushort4*)(Al + r*32 + c4) = lv;
      }
    }
    // ---- stage B via global_load_lds: wave wid loads 16-row segment wid ----
    {
      int row = wid * 16 + srow;
      const unsigned short* gh = Wh + (size_t)(n0 + row) * HIDDEN + k0 + skoff;
      gl_lds16(gh, Bh + wid * 512);
      if (SPLITS >= 3){
        const unsigned short* gl = Wl + (size_t)(n0 + row) * HIDDEN + k0 + skoff;
        gl_lds16(gl, Bl + wid * 512);
      }
    }
    __syncthreads();

    s16x8 ah[2], al[2], bh[4], bl[4];
    #pragma unroll
    for (int i = 0; i < 2; i++){
      ah[i] = *(const s16x8*)(Ah + (wm*32 + i*16 + l16)*32 + quad*8);
      if (SPLITS >= 3) al[i] = *(const s16x8*)(Al + (wm*32 + i*16 + l16)*32 + quad*8);
    }
    #pragma unroll
    for (int j = 0; j < 4; j++){
      bh[j] = *(const s16x8*)(Bh + (wn*64 + j*16 + l16)*32 + quad*8);
      if (SPLITS >= 3) bl[j] = *(const s16x8*)(Bl + (wn*64 + j*16 + l16)*32 + quad*8);
    }
    #pragma unroll
    for (int i = 0; i < 2; i++)
      #pragma unroll
      for (int j = 0; j < 4; j++){
        acc[i][j] = __builtin_amdgcn_mfma_f32_16x16x32_bf16(ah[i], bh[j], acc[i][j], 0, 0, 0);
        if (SPLITS >= 3){
          acc[i][j] = __builtin_amdgcn_mfma_f32_16x16x32_bf16(ah[i], bl[j], acc[i][j], 0, 0, 0);
          acc[i][j] = __builtin_amdgcn_mfma_f32_16x16x32_bf16(al[i], bh[j], acc[i][j], 0, 0, 0);
        }
      }
    __syncthreads();
  }

  if (MODE == 0){
    #pragma unroll
    for (int i = 0; i < 2; i++)
      #pragma unroll
      for (int j = 0; j < 4; j++)
        #pragma unroll
        for (int r = 0; r < 4; r++){
          int m = m0 + wm*32 + i*16 + quad*4 + r;
          int n = n0 + wn*64 + j*16 + l16;
          float c = acc[i][j][r];
          unsigned short h = f2bf(c);
          Ohi[(size_t)m * HEADD + n] = h;
          Olo[(size_t)m * HEADD + n] = f2bf(c - bf2f(h));
        }
  } else {
    #pragma unroll
    for (int i = 0; i < 2; i++)
      #pragma unroll
      for (int j = 0; j < 4; j++){
        int mbase = m0 + wm*32 + i*16 + quad*4;
        int d = n0 + wn*64 + j*16 + l16;
        int b = mbase >> 11;        // /2048
        int t = mbase & 2047;
        ushort4 vv;
        vv.x = f2bf(acc[i][j][0]);
        vv.y = f2bf(acc[i][j][1]);
        vv.z = f2bf(acc[i][j][2]);
        vv.w = f2bf(acc[i][j][3]);
        *(ushort4*)(OvT + ((size_t)(b * HEADD + d)) * SEQ + t) = vv;
      }
  }
}

// ---------------- Kernel 3: flash attention ----------------
// grid (128 q-tiles, 4 batches), 512 threads = 8 waves. Q-tile = 16 rows (shared by all
// waves), K-tile = 256 keys/iter staged hi/lo into LDS via global_load_lds in 64-d chunks.
// QK: wave w owns keys [w*32, w*32+32), 4-term split-bf16. PV: wave w owns dims [w*64, w*64+64).
__global__ __launch_bounds__(512, 4)
void flash_kernel(const unsigned short* __restrict__ qhh, const unsigned short* __restrict__ qhl,
                  const unsigned short* __restrict__ khh, const unsigned short* __restrict__ khl,
                  const unsigned short* __restrict__ vhT, const int* __restrict__ mask,
                  float* __restrict__ out){
  __shared__ unsigned short KhA[FK*32], KhB[FK*32];   // K hi, d-subchunks A/B of 64-d chunk
  __shared__ unsigned short KlA[FK*32], KlB[FK*32];   // K lo
  __shared__ unsigned short Pls[16*272];              // P, padded stride 272 (16B-aligned)
  __shared__ float redm[8][16], reds[8][16];
  __shared__ float m_row[16], l_row[16], mnew_s[16], alpha_s[16];

  const int tid = threadIdx.x, lane = tid & 63, wid = tid >> 6;  // 8 waves
  const int quad = lane >> 4, l16 = lane & 15;
  const int b = blockIdx.y, q0 = blockIdx.x * 16;
  const int srow  = lane >> 2;        // staging row within 16-key segment
  const int skoff = (lane & 3) << 3;  // staging k-dim offset (shorts)

  if (tid < 16){ m_row[tid] = -3.0e38f; l_row[tid] = 0.f; }
  f32x4 oacc[4];
  #pragma unroll
  for (int j = 0; j < 4; j++){
    f32x4 z = {0.f, 0.f, 0.f, 0.f};
    oacc[j] = z;
  }

  const size_t qrow = ((size_t)(b * SEQ) + q0 + l16) * HEADD;   // + c*64 + ds*32 + quad*8

  for (int kb = 0; kb < SEQ; kb += FK){
    f32x4 s0 = {0.f,0.f,0.f,0.f}, s1 = {0.f,0.f,0.f,0.f};
    // ---- QK^T over d in 64-wide chunks, K staged in LDS ----
    for (int c = 0; c < 8; c++){
      #pragma unroll
      for (int sg = 0; sg < 2; sg++){
        int seg = wid*2 + sg;
        int key = kb + seg*16 + srow;
        const unsigned short* gh = khh + ((size_t)(b * SEQ) + key) * HEADD + c*64 + skoff;
        const unsigned short* gl = khl + ((size_t)(b * SEQ) + key) * HEADD + c*64 + skoff;
        gl_lds16(gh,      KhA + seg*512);
        gl_lds16(gh + 32, KhB + seg*512);
        gl_lds16(gl,      KlA + seg*512);
        gl_lds16(gl + 32, KlB + seg*512);
      }
      __syncthreads();
      #pragma unroll
      for (int ds = 0; ds < 2; ds++){
        const unsigned short* KH = ds ? KhB : KhA;
        const unsigned short* KL = ds ? KlB : KlA;
        s16x8 aH = *(const s16x8*)(qhh + qrow + c*64 + ds*32 + quad*8);
        s16x8 aL = *(const s16x8*)(qhl + qrow + c*64 + ds*32 + quad*8);
        s16x8 b0H = *(const s16x8*)(KH + (wid*32 + l16)*32 + quad*8);
        s16x8 b0L = *(const s16x8*)(KL + (wid*32 + l16)*32 + quad*8);
        s16x8 b1H = *(const s16x8*)(KH + (wid*32 + 16 + l16)*32 + quad*8);
        s16x8 b1L = *(const s16x8*)(KL + (wid*32 + 16 + l16)*32 + quad*8);
        s0 = __builtin_amdgcn_mfma_f32_16x16x32_bf16(aH, b0H, s0, 0, 0, 0);
        s0 = __builtin_amdgcn_mfma_f32_16x16x32_bf16(aH, b0L, s0, 0, 0, 0);
        s0 = __builtin_amdgcn_mfma_f32_16x16x32_bf16(aL, b0H, s0, 0, 0, 0);
        s0 = __builtin_amdgcn_mfma_f32_16x16x32_bf16(aL, b0L, s0, 0, 0, 0);
        s1 = __builtin_amdgcn_mfma_f32_16x16x32_bf16(aH, b1H, s1, 0, 0, 0);
        s1 = __builtin_amdgcn_mfma_f32_16x16x32_bf16(aH, b1L, s1, 0, 0, 0);
        s1 = __builtin_amdgcn_mfma_f32_16x16x32_bf16(aL, b1H, s1, 0, 0, 0);
        s1 = __builtin_amdgcn_mfma_f32_16x16x32_bf16(aL, b1L, s1, 0, 0, 0);
      }
      __syncthreads();
    }
    // ---- scale + mask ----
    const int key0 = kb + wid*32 + l16;
    const int mk0 = mask[b * SEQ + key0];
    const int mk1 = mask[b * SEQ + key0 + 16];
    float sm0[4], sm1[4];
    #pragma unroll
    for (int r = 0; r < 4; r++){
      sm0[r] = mk0 ? s0[r] * 64.0f : -1.0e9f;
      sm1[r] = mk1 ? s1[r] * 64.0f : -1.0e9f;
    }
    // ---- per-wave row max over its 32 keys ----
    float rm[4];
    #pragma unroll
    for (int r = 0; r < 4; r++) rm[r] = fmaxf(sm0[r], sm1[r]);
    #pragma unroll
    for (int sh = 1; sh < 16; sh <<= 1){
      #pragma unroll
      for (int r = 0; r < 4; r++) rm[r] = fmaxf(rm[r], __shfl_xor(rm[r], sh, 64));
    }
    if (l16 == 0){
      #pragma unroll
      for (int r = 0; r < 4; r++) redm[wid][quad*4 + r] = rm[r];
    }
    __syncthreads();
    if (tid < 16){
      float mt = redm[0][tid];
      #pragma unroll
      for (int w = 1; w < 8; w++) mt = fmaxf(mt, redm[w][tid]);
      float mo = m_row[tid];
      float mn = fmaxf(mo, mt);
      mnew_s[tid]  = mn;
      alpha_s[tid] = __expf(mo - mn);
      m_row[tid]   = mn;
    }
    __syncthreads();
    // ---- p = exp(s - m_new) -> LDS, row sums; rescale O ----
    float rs[4];
    #pragma unroll
    for (int r = 0; r < 4; r++){
      int row = quad*4 + r;
      float mn = mnew_s[row];
      float p0 = __expf(sm0[r] - mn);
      float p1 = __expf(sm1[r] - mn);
      rs[r] = p0 + p1;
      Pls[row*272 + wid*32 + l16]      = f2bf(p0);
      Pls[row*272 + wid*32 + 16 + l16] = f2bf(p1);
    }
    #pragma unroll
    for (int sh = 1; sh < 16; sh <<= 1){
      #pragma unroll
      for (int r = 0; r < 4; r++) rs[r] += __shfl_xor(rs[r], sh, 64);
    }
    if (l16 == 0){
      #pragma unroll
      for (int r = 0; r < 4; r++) reds[wid][quad*4 + r] = rs[r];
    }
    {
      float aa[4];
      #pragma unroll
      for (int r = 0; r < 4; r++) aa[r] = alpha_s[quad*4 + r];
      #pragma unroll
      for (int j = 0; j < 4; j++)
        #pragma unroll
        for (int r = 0; r < 4; r++) oacc[j][r] *= aa[r];
    }
    __syncthreads();
    if (tid < 16){
      float lacc = l_row[tid] * alpha_s[tid];
      #pragma unroll
      for (int w = 0; w < 8; w++) lacc += reds[w][tid];
      l_row[tid] = lacc;
    }
    // ---- PV: wave owns d-range [wid*64, wid*64+64) ----
    #pragma unroll
    for (int ks = 0; ks < 8; ks++){
      s16x8 pa = *(const s16x8*)(Pls + l16*272 + ks*32 + quad*8);
      #pragma unroll
      for (int j = 0; j < 4; j++){
        int d = wid*64 + j*16 + l16;
        s16x8 vb = *(const s16x8*)(vhT + ((size_t)(b * HEADD + d)) * SEQ + kb + ks*32 + quad*8);
        oacc[j] = __builtin_amdgcn_mfma_f32_16x16x32_bf16(pa, vb, oacc[j], 0, 0, 0);
      }
    }
    __syncthreads();
  }

  // ---- epilogue ----
  float inv[4];
  #pragma unroll
  for (int r = 0; r < 4; r++) inv[r] = 1.0f / l_row[quad*4 + r];
  #pragma unroll
  for (int j = 0; j < 4; j++)
    #pragma unroll
    for (int r = 0; r < 4; r++){
      int qrow_o = q0 + quad*4 + r;
      int d = wid*64 + j*16 + l16;
      out[((size_t)(b * SEQ) + qrow_o) * HEADD + d] = oacc[j][r] * inv[r];
    }
}

extern "C" void kernel_launch(void* const* d_in, const int* in_sizes, int n_in,
                              void* d_out, int out_size, void* d_ws, size_t ws_size,
                              hipStream_t stream){
  const float* q    = (const float*)d_in[0];
  const float* k    = (const float*)d_in[1];
  const float* v    = (const float*)d_in[2];
  const int*   mask = (const int*)d_in[3];
  const float* Wq   = (const float*)d_in[4];
  const float* Wk   = (const float*)d_in[5];
  const float* Wv   = (const float*)d_in[6];
  float* out = (float*)d_out;

  char* ws = (char*)d_ws;
  const size_t MB = 1024 * 1024;
  unsigned short* wqh = (unsigned short*)(ws + 0*MB);
  unsigned short* wql = (unsigned short*)(ws + 4*MB);
  unsigned short* wkh = (unsigned short*)(ws + 8*MB);
  unsigned short* wkl = (unsigned short*)(ws + 12*MB);
  unsigned short* wvh = (unsigned short*)(ws + 16*MB);
  unsigned short* qhh = (unsigned short*)(ws + 20*MB);
  unsigned short* qhl = (unsigned short*)(ws + 28*MB);
  unsigned short* khh = (unsigned short*)(ws + 36*MB);
  unsigned short* khl = (unsigned short*)(ws + 44*MB);
  unsigned short* vhT = (unsigned short*)(ws + 52*MB);  // total 60 MB

  hipLaunchKernelGGL(wsplit_kernel, dim3(1024), dim3(256), 0, stream,
                     Wq, Wk, Wv, wqh, wql, wkh, wkl, wvh);
  hipLaunchKernelGGL((proj_kernel<3,0>), dim3(4, 64), dim3(512), 0, stream,
                     q, wqh, wql, qhh, qhl, (unsigned short*)nullptr);
  hipLaunchKernelGGL((proj_kernel<3,0>), dim3(4, 64), dim3(512), 0, stream,
                     k, wkh, wkl, khh, khl, (unsigned short*)nullptr);
  hipLaunchKernelGGL((proj_kernel<1,1>), dim3(4, 64), dim3(512), 0, stream,
                     v, wvh, wvh, (unsigned short*)nullptr, (unsigned short*)nullptr, vhT);
  hipLaunchKernelGGL(flash_kernel, dim3(SEQ/16, NBATCH), dim3(512), 0, stream,
                     qhh, qhl, khh, khl, vhT, mask, out);
}

// Round 3
// 919.464 us; speedup vs baseline: 1.5451x; 1.3595x over previous
//
#include <hip/hip_runtime.h>

#define HIDDEN 4096
#define HEADD  512
#define SEQ    2048
#define NBATCH 4
#define KSPLIT 4
#define KRANGE (SEQ/KSPLIT)   // 512 keys per flash block
#define KSTR   520            // padded K row stride in LDS (shorts): 2-way banks

typedef float f32x4 __attribute__((ext_vector_type(4)));
typedef short s16x8 __attribute__((ext_vector_type(8)));

__device__ __forceinline__ unsigned short f2bf(float x){
  unsigned u = __float_as_uint(x);
  u += 0x7fffu + ((u >> 16) & 1u);
  return (unsigned short)(u >> 16);
}
__device__ __forceinline__ float bf2f(unsigned short b){
  return __uint_as_float(((unsigned)b) << 16);
}
// async global->LDS, 16B/lane. LDS base wave-uniform; lane i lands at base + i*16.
__device__ __forceinline__ void gl_lds16(const unsigned short* g, unsigned short* l){
  __builtin_amdgcn_global_load_lds((const __attribute__((address_space(1))) unsigned int*)g,
                                   (__attribute__((address_space(3))) unsigned int*)l,
                                   16, 0, 0);
}

// ---------------- Kernel 1: split weights fp32 -> bf16 hi/lo ----------------
__global__ void wsplit_kernel(const float* __restrict__ Wq,
                              const float* __restrict__ Wk,
                              const float* __restrict__ Wv,
                              unsigned short* __restrict__ wqh, unsigned short* __restrict__ wql,
                              unsigned short* __restrict__ wkh, unsigned short* __restrict__ wkl,
                              unsigned short* __restrict__ wvh){
  const int n = HEADD * HIDDEN;
  for (int i = blockIdx.x * blockDim.x + threadIdx.x; i < n; i += gridDim.x * blockDim.x){
    float a = Wq[i]; unsigned short h = f2bf(a);
    wqh[i] = h; wql[i] = f2bf(a - bf2f(h));
    a = Wk[i]; h = f2bf(a);
    wkh[i] = h; wkl[i] = f2bf(a - bf2f(h));
    wvh[i] = f2bf(Wv[i]);
  }
}

// ---------------- Kernel 2: projection GEMM C[8192,512] = X[8192,4096]*W[512,4096]^T
// BK=64 via two 32-wide half-buffers. B via global_load_lds. A fp32 register-prefetched
// across the barrier; fp32->hi/lo conversion overlaps previous iter's MFMA.
template<int SPLITS, int MODE>
__global__ __launch_bounds__(512, 4)
void proj_kernel(const float* __restrict__ X,
                 const unsigned short* __restrict__ Wh,
                 const unsigned short* __restrict__ Wl,
                 unsigned short* __restrict__ Ohi,
                 unsigned short* __restrict__ Olo,
                 unsigned short* __restrict__ OvT){
  __shared__ unsigned short Ah[2][128*32];
  __shared__ unsigned short Al[(SPLITS>=3)?2*128*32:8];
  __shared__ unsigned short Bh[2][128*32];
  __shared__ unsigned short Bl[(SPLITS>=3)?2*128*32:8];

  const int tid  = threadIdx.x;
  const int lane = tid & 63, wid = tid >> 6;      // 8 waves
  const int quad = lane >> 4, l16 = lane & 15;
  const int wm = wid >> 1, wn = wid & 1;          // 4 x 2 wave grid, wave tile 32x64
  const int m0 = blockIdx.y * 128, n0 = blockIdx.x * 128;
  const int brow = lane >> 2;                      // B staging row within 16-row seg
  const int bcol = (lane & 3) << 3;                // B staging col (shorts)

  f32x4 acc[2][4];
  #pragma unroll
  for (int i = 0; i < 2; i++)
    #pragma unroll
    for (int j = 0; j < 4; j++){
      f32x4 z = {0.f, 0.f, 0.f, 0.f};
      acc[i][j] = z;
    }

  // A prefetch registers: 4 chunks of float4 per thread covering 128x64 fp32
  float4 xa[4];
  int ar[4], ahalf[4], acin[4];
  #pragma unroll
  for (int c = 0; c < 4; c++){
    int chunk = tid + c * 512;
    ar[c]    = chunk >> 4;
    int col4 = (chunk & 15) << 2;
    ahalf[c] = col4 >> 5;
    acin[c]  = col4 & 31;
    xa[c] = *(const float4*)(X + (size_t)(m0 + ar[c]) * HIDDEN + col4);
  }

  for (int k0 = 0; k0 < HIDDEN; k0 += 64){
    // ---- stage A from regs (fp32 -> hi/lo) ----
    #pragma unroll
    for (int c = 0; c < 4; c++){
      ushort4 hv;
      hv.x = f2bf(xa[c].x); hv.y = f2bf(xa[c].y); hv.z = f2bf(xa[c].z); hv.w = f2bf(xa[c].w);
      *(ushort4*)(&Ah[ahalf[c]][ar[c]*32 + acin[c]]) = hv;
      if (SPLITS >= 3){
        ushort4 lv;
        lv.x = f2bf(xa[c].x - bf2f(hv.x));
        lv.y = f2bf(xa[c].y - bf2f(hv.y));
        lv.z = f2bf(xa[c].z - bf2f(hv.z));
        lv.w = f2bf(xa[c].w - bf2f(hv.w));
        *(ushort4*)(&Al[ahalf[c]*4096 + ar[c]*32 + acin[c]]) = lv;
      }
    }
    // ---- stage B via global_load_lds: wave wid stages rows [wid*16,+16) per half ----
    #pragma unroll
    for (int h = 0; h < 2; h++){
      const unsigned short* gh = Wh + (size_t)(n0 + wid*16 + brow) * HIDDEN + k0 + h*32 + bcol;
      gl_lds16(gh, &Bh[h][wid*512]);
      if (SPLITS >= 3){
        const unsigned short* gl = Wl + (size_t)(n0 + wid*16 + brow) * HIDDEN + k0 + h*32 + bcol;
        gl_lds16(gl, &Bl[h*4096 + wid*512]);
      }
    }
    __syncthreads();
    // ---- prefetch next A (flies during MFMA) ----
    if (k0 + 64 < HIDDEN){
      #pragma unroll
      for (int c = 0; c < 4; c++){
        int col4 = ahalf[c]*32 + acin[c];
        xa[c] = *(const float4*)(X + (size_t)(m0 + ar[c]) * HIDDEN + k0 + 64 + col4);
      }
    }
    // ---- compute both halves ----
    #pragma unroll
    for (int h = 0; h < 2; h++){
      s16x8 ah[2], al[2], bh[4], bl[4];
      #pragma unroll
      for (int i = 0; i < 2; i++){
        ah[i] = *(const s16x8*)(&Ah[h][(wm*32 + i*16 + l16)*32 + quad*8]);
        if (SPLITS >= 3) al[i] = *(const s16x8*)(&Al[h*4096 + (wm*32 + i*16 + l16)*32 + quad*8]);
      }
      #pragma unroll
      for (int j = 0; j < 4; j++){
        bh[j] = *(const s16x8*)(&Bh[h][(wn*64 + j*16 + l16)*32 + quad*8]);
        if (SPLITS >= 3) bl[j] = *(const s16x8*)(&Bl[h*4096 + (wn*64 + j*16 + l16)*32 + quad*8]);
      }
      #pragma unroll
      for (int i = 0; i < 2; i++)
        #pragma unroll
        for (int j = 0; j < 4; j++){
          acc[i][j] = __builtin_amdgcn_mfma_f32_16x16x32_bf16(ah[i], bh[j], acc[i][j], 0, 0, 0);
          if (SPLITS >= 3){
            acc[i][j] = __builtin_amdgcn_mfma_f32_16x16x32_bf16(ah[i], bl[j], acc[i][j], 0, 0, 0);
            acc[i][j] = __builtin_amdgcn_mfma_f32_16x16x32_bf16(al[i], bh[j], acc[i][j], 0, 0, 0);
          }
        }
    }
    __syncthreads();
  }

  if (MODE == 0){
    #pragma unroll
    for (int i = 0; i < 2; i++)
      #pragma unroll
      for (int j = 0; j < 4; j++)
        #pragma unroll
        for (int r = 0; r < 4; r++){
          int m = m0 + wm*32 + i*16 + quad*4 + r;
          int n = n0 + wn*64 + j*16 + l16;
          float c = acc[i][j][r];
          unsigned short h = f2bf(c);
          Ohi[(size_t)m * HEADD + n] = h;
          Olo[(size_t)m * HEADD + n] = f2bf(c - bf2f(h));
        }
  } else {
    #pragma unroll
    for (int i = 0; i < 2; i++)
      #pragma unroll
      for (int j = 0; j < 4; j++){
        int mbase = m0 + wm*32 + i*16 + quad*4;
        int d = n0 + wn*64 + j*16 + l16;
        int b = mbase >> 11;
        int t = mbase & 2047;
        ushort4 vv;
        vv.x = f2bf(acc[i][j][0]);
        vv.y = f2bf(acc[i][j][1]);
        vv.z = f2bf(acc[i][j][2]);
        vv.w = f2bf(acc[i][j][3]);
        *(ushort4*)(OvT + ((size_t)(b * HEADD + d)) * SEQ + t) = vv;
      }
  }
}

// ---------------- Kernel 3: flash attention, per-wave q-ownership + K-split ----
// grid (16 q-tiles, KSPLIT, 4 batches), 512 threads = 8 waves. Wave owns 16 q rows:
// full O[16x512] accumulator in regs, wave-local online softmax (no cross-wave reduce).
// K-tile = 32 keys full-d (hi+lo) + V-tile shared in LDS; 2 barriers per 32 keys.
__global__ __launch_bounds__(512, 2)
void flash_kernel(const unsigned short* __restrict__ qhh, const unsigned short* __restrict__ qhl,
                  const unsigned short* __restrict__ khh, const unsigned short* __restrict__ khl,
                  const unsigned short* __restrict__ vhT, const int* __restrict__ mask,
                  float* __restrict__ part, float* __restrict__ ml){
  __shared__ unsigned short Kh[32*KSTR];   // 33.3 KB, padded stride
  __shared__ unsigned short Kl[32*KSTR];
  __shared__ unsigned short Vt[512*32];    // 32 KB, [d][k]
  __shared__ unsigned short Pt[8*512];     // 8 KB, per-wave 16x32

  const int tid = threadIdx.x, lane = tid & 63, wid = tid >> 6;
  const int quad = lane >> 4, l16 = lane & 15;
  const int b = blockIdx.z, kz = blockIdx.y;
  const int qrow0 = blockIdx.x * 128 + wid * 16;   // wave's 16 q rows
  const int kbase = kz * KRANGE;

  // resident Q-hi fragments (64 VGPRs); Q-lo re-read from global per tile
  const size_t qoff = ((size_t)(b * SEQ) + qrow0 + l16) * HEADD + quad * 8;
  s16x8 qh[16];
  #pragma unroll
  for (int ds = 0; ds < 16; ds++) qh[ds] = *(const s16x8*)(qhh + qoff + ds*32);

  float mrow[4], lrow[4];
  #pragma unroll
  for (int r = 0; r < 4; r++){ mrow[r] = -3.0e38f; lrow[r] = 0.f; }
  f32x4 oacc[32];
  #pragma unroll
  for (int j = 0; j < 32; j++){
    f32x4 z = {0.f, 0.f, 0.f, 0.f};
    oacc[j] = z;
  }

  for (int kt = 0; kt < KRANGE; kt += 32){
    __syncthreads();   // all waves done reading previous K/V tile
    // ---- stage K: wave stages keys [wid*4, wid*4+4), one 1KB row per call ----
    #pragma unroll
    for (int c = 0; c < 4; c++){
      int keyl = wid*4 + c;
      size_t g = ((size_t)(b * SEQ) + kbase + kt + keyl) * HEADD + lane*8;
      gl_lds16(khh + g, Kh + keyl*KSTR);
      gl_lds16(khl + g, Kl + keyl*KSTR);
    }
    // ---- stage V: wave stages d rows [wid*64, +64), 16 rows (64B each) per call ----
    #pragma unroll
    for (int c = 0; c < 4; c++){
      int d0 = wid*64 + c*16;
      const unsigned short* vs = vhT + ((size_t)(b * HEADD) + d0 + (lane>>2)) * SEQ
                                     + kbase + kt + (lane & 3)*8;
      gl_lds16(vs, Vt + d0*32);
    }
    __syncthreads();   // staging drained (vmcnt(0) before barrier)

    // ---- QK^T: S[16 x 32] per wave, 4-term split ----
    f32x4 s0 = {0.f,0.f,0.f,0.f}, s1 = {0.f,0.f,0.f,0.f};
    #pragma unroll
    for (int ds = 0; ds < 16; ds++){
      s16x8 aL  = *(const s16x8*)(qhl + qoff + ds*32);
      s16x8 b0H = *(const s16x8*)(Kh + l16*KSTR      + ds*32 + quad*8);
      s16x8 b0L = *(const s16x8*)(Kl + l16*KSTR      + ds*32 + quad*8);
      s16x8 b1H = *(const s16x8*)(Kh + (16+l16)*KSTR + ds*32 + quad*8);
      s16x8 b1L = *(const s16x8*)(Kl + (16+l16)*KSTR + ds*32 + quad*8);
      s0 = __builtin_amdgcn_mfma_f32_16x16x32_bf16(qh[ds], b0H, s0, 0, 0, 0);
      s0 = __builtin_amdgcn_mfma_f32_16x16x32_bf16(qh[ds], b0L, s0, 0, 0, 0);
      s0 = __builtin_amdgcn_mfma_f32_16x16x32_bf16(aL,     b0H, s0, 0, 0, 0);
      s0 = __builtin_amdgcn_mfma_f32_16x16x32_bf16(aL,     b0L, s0, 0, 0, 0);
      s1 = __builtin_amdgcn_mfma_f32_16x16x32_bf16(qh[ds], b1H, s1, 0, 0, 0);
      s1 = __builtin_amdgcn_mfma_f32_16x16x32_bf16(qh[ds], b1L, s1, 0, 0, 0);
      s1 = __builtin_amdgcn_mfma_f32_16x16x32_bf16(aL,     b1H, s1, 0, 0, 0);
      s1 = __builtin_amdgcn_mfma_f32_16x16x32_bf16(aL,     b1L, s1, 0, 0, 0);
    }
    // ---- scale + mask ----
    const int key0 = kbase + kt + l16;
    const int mk0 = mask[b * SEQ + key0];
    const int mk1 = mask[b * SEQ + key0 + 16];
    float sm0[4], sm1[4];
    #pragma unroll
    for (int r = 0; r < 4; r++){
      sm0[r] = mk0 ? s0[r] * 64.0f : -1.0e9f;
      sm1[r] = mk1 ? s1[r] * 64.0f : -1.0e9f;
    }
    // ---- wave-local online softmax (rows quad*4+r, reduce over 16 lanes) ----
    float rm[4];
    #pragma unroll
    for (int r = 0; r < 4; r++) rm[r] = fmaxf(sm0[r], sm1[r]);
    #pragma unroll
    for (int sh = 1; sh < 16; sh <<= 1){
      #pragma unroll
      for (int r = 0; r < 4; r++) rm[r] = fmaxf(rm[r], __shfl_xor(rm[r], sh, 64));
    }
    float alpha[4], p0[4], p1[4], rs[4];
    #pragma unroll
    for (int r = 0; r < 4; r++){
      float mn = fmaxf(mrow[r], rm[r]);
      alpha[r] = __expf(mrow[r] - mn);
      mrow[r] = mn;
      p0[r] = __expf(sm0[r] - mn);
      p1[r] = __expf(sm1[r] - mn);
      rs[r] = p0[r] + p1[r];
    }
    #pragma unroll
    for (int sh = 1; sh < 16; sh <<= 1){
      #pragma unroll
      for (int r = 0; r < 4; r++) rs[r] += __shfl_xor(rs[r], sh, 64);
    }
    #pragma unroll
    for (int r = 0; r < 4; r++) lrow[r] = lrow[r] * alpha[r] + rs[r];
    // ---- P -> per-wave LDS (C-layout write, A-layout read; no barrier needed) ----
    #pragma unroll
    for (int r = 0; r < 4; r++){
      Pt[wid*512 + (quad*4 + r)*32 + l16]      = f2bf(p0[r]);
      Pt[wid*512 + (quad*4 + r)*32 + 16 + l16] = f2bf(p1[r]);
    }
    // ---- rescale O ----
    #pragma unroll
    for (int j = 0; j < 32; j++)
      #pragma unroll
      for (int r = 0; r < 4; r++) oacc[j][r] *= alpha[r];
    // ---- PV: O[16x512] += P[16x32] * V[32x512] ----
    s16x8 pa = *(const s16x8*)(Pt + wid*512 + l16*32 + quad*8);
    #pragma unroll
    for (int j = 0; j < 32; j++){
      s16x8 vb = *(const s16x8*)(Vt + (j*16 + l16)*32 + quad*8);
      oacc[j] = __builtin_amdgcn_mfma_f32_16x16x32_bf16(pa, vb, oacc[j], 0, 0, 0);
    }
  }

  // ---- write fp32 partials + (m,l) ----
  const size_t prow = (size_t)(kz * (NBATCH*SEQ)) + b * SEQ + qrow0;
  #pragma unroll
  for (int j = 0; j < 32; j++)
    #pragma unroll
    for (int r = 0; r < 4; r++)
      part[(prow + quad*4 + r) * HEADD + j*16 + l16] = oacc[j][r];
  if (l16 == 0){
    #pragma unroll
    for (int r = 0; r < 4; r++){
      ml[(prow + quad*4 + r)*2 + 0] = mrow[r];
      ml[(prow + quad*4 + r)*2 + 1] = lrow[r];
    }
  }
}

// ---------------- Kernel 4: combine KSPLIT partials ----------------
__global__ __launch_bounds__(256)
void reduce_kernel(const float* __restrict__ part, const float* __restrict__ ml,
                   float* __restrict__ out){
  const int row = blockIdx.x;            // b*SEQ + s in [0, 8192)
  const int t = threadIdx.x;
  float m[KSPLIT], l[KSPLIT];
  float M = -3.0e38f;
  #pragma unroll
  for (int j = 0; j < KSPLIT; j++){
    m[j] = ml[((size_t)j*(NBATCH*SEQ) + row)*2 + 0];
    l[j] = ml[((size_t)j*(NBATCH*SEQ) + row)*2 + 1];
    M = fmaxf(M, m[j]);
  }
  float w[KSPLIT], L = 0.f;
  #pragma unroll
  for (int j = 0; j < KSPLIT; j++){
    w[j] = __expf(m[j] - M);
    L += w[j] * l[j];
  }
  const float invL = 1.0f / L;
  #pragma unroll
  for (int c = 0; c < 2; c++){
    int d = t + c*256;
    float acc = 0.f;
    #pragma unroll
    for (int j = 0; j < KSPLIT; j++)
      acc += w[j] * part[((size_t)j*(NBATCH*SEQ) + row)*HEADD + d];
    out[(size_t)row * HEADD + d] = acc * invL;
  }
}

extern "C" void kernel_launch(void* const* d_in, const int* in_sizes, int n_in,
                              void* d_out, int out_size, void* d_ws, size_t ws_size,
                              hipStream_t stream){
  const float* q    = (const float*)d_in[0];
  const float* k    = (const float*)d_in[1];
  const float* v    = (const float*)d_in[2];
  const int*   mask = (const int*)d_in[3];
  const float* Wq   = (const float*)d_in[4];
  const float* Wk   = (const float*)d_in[5];
  const float* Wv   = (const float*)d_in[6];
  float* out = (float*)d_out;

  char* ws = (char*)d_ws;
  const size_t MB = 1024 * 1024;
  unsigned short* wqh = (unsigned short*)(ws + 0*MB);
  unsigned short* wql = (unsigned short*)(ws + 4*MB);
  unsigned short* wkh = (unsigned short*)(ws + 8*MB);
  unsigned short* wkl = (unsigned short*)(ws + 12*MB);
  unsigned short* wvh = (unsigned short*)(ws + 16*MB);
  unsigned short* qhh = (unsigned short*)(ws + 20*MB);
  unsigned short* qhl = (unsigned short*)(ws + 28*MB);
  unsigned short* khh = (unsigned short*)(ws + 36*MB);
  unsigned short* khl = (unsigned short*)(ws + 44*MB);
  unsigned short* vhT = (unsigned short*)(ws + 52*MB);
  float*          part = (float*)(ws + 60*MB);          // KSPLIT*8192*512 fp32 = 64 MB
  float*          mlb  = (float*)(ws + 124*MB);         // KSPLIT*8192*2 fp32 = 256 KB

  hipLaunchKernelGGL(wsplit_kernel, dim3(1024), dim3(256), 0, stream,
                     Wq, Wk, Wv, wqh, wql, wkh, wkl, wvh);
  hipLaunchKernelGGL((proj_kernel<3,0>), dim3(4, 64), dim3(512), 0, stream,
                     q, wqh, wql, qhh, qhl, (unsigned short*)nullptr);
  hipLaunchKernelGGL((proj_kernel<3,0>), dim3(4, 64), dim3(512), 0, stream,
                     k, wkh, wkl, khh, khl, (unsigned short*)nullptr);
  hipLaunchKernelGGL((proj_kernel<1,1>), dim3(4, 64), dim3(512), 0, stream,
                     v, wvh, wvh, (unsigned short*)nullptr, (unsigned short*)nullptr, vhT);
  hipLaunchKernelGGL(flash_kernel, dim3(SEQ/128, KSPLIT, NBATCH), dim3(512), 0, stream,
                     qhh, qhl, khh, khl, vhT, mask, part, mlb);
  hipLaunchKernelGGL(reduce_kernel, dim3(NBATCH*SEQ), dim3(256), 0, stream,
                     part, mlb, out);
}